// Round 10
// baseline (260.504 us; speedup 1.0000x reference)
//
#include <hip/hip_runtime.h>
#include <float.h>

#define NV 4096
#define OSTRIDE 451
#define NT 512
typedef unsigned long long u64;

// key = (float-bits(d2) << 32) | idx. d2 >= 0 so float bits are monotone in
// value -> u64 compare == exact lexicographic (d2, idx) compare == top_k's
// stable tie semantics.
__device__ __forceinline__ u64 packkey(float d, int idx) {
    return ((u64)__float_as_uint(d) << 32) | (u64)(unsigned)idx;
}

__device__ __forceinline__ void cswap(u64& a, u64& b) {
    bool c = a < b;
    u64 lo = c ? a : b;
    u64 hi = c ? b : a;
    a = lo; b = hi;
}

// sorted ascending insert of ck (caller guarantees ck < k[7]); drops k[7]
__device__ __forceinline__ void ins8(u64 (&k)[8], u64 ck) {
    bool b[7];
#pragma unroll
    for (int q = 0; q < 7; ++q) b[q] = ck < k[q];
#pragma unroll
    for (int q = 7; q >= 1; --q) {
        bool hi = (q == 7) ? true : b[q];
        k[q] = b[q-1] ? k[q-1] : (hi ? ck : k[q]);
    }
    k[0] = b[0] ? ck : k[0];
}

// wave-uniform event loop with post-insert refilter (prunes seed storms)
__device__ __forceinline__ void handle8(u64 mask, float dj, int jj, int ob,
                                        u64 (&k)[8], float& T) {
    while (mask) {
        int l = __builtin_ctzll(mask);
        mask &= mask - 1;
        int cm = ob + 8*l + jj;
        if (cm < 8) continue;                      // seed points already in list
        float cd = __uint_as_float(__builtin_amdgcn_readlane(__float_as_uint(dj), l));
        u64 ck = packkey(cd, cm);
        if (ck < k[7]) {
            ins8(k, ck);
            T = __uint_as_float((unsigned)(k[7] >> 32));
            mask &= __ballot(dj <= T);             // refilter vs tightened T
        }
    }
}

// weight: reference recomputes dist2 from vec = nbr - vert, numpy op order
// (round products, sequential add, no fma), w = 1/(1+dist2)
template<int M>
__device__ __forceinline__ float wcalc(const float* __restrict__ pc, int m,
                                       float vx, float vy, float vz) {
    float qx = pc[m], qy = pc[M+m], qz = pc[2*M+m];
    float dx = __fsub_rn(qx, vx), dy = __fsub_rn(qy, vy), dz = __fsub_rn(qz, vz);
    float dist2 = __fadd_rn(__fadd_rn(__fmul_rn(dx,dx), __fmul_rn(dy,dy)),
                            __fmul_rn(dz,dz));
    return __fdiv_rn(1.0f, __fadd_rn(1.0f, dist2));
}

// One wave, ONE (vertex, stage) pair, full scan (PARTS=1: minimal events, no
// merges, no LDS, no barriers). Lanes process 8 consecutive points per
// 512-point batch (6 float4 loads, 1-deep prefetch). Top-8 = wave-uniform
// u64 keys; all branches wave-uniform. Selection distance = direct form
// (p-v).(p-v): abs err ~ulp(d2), ~500x tighter than the reference's
// cancellation form -> matches the f64-arbiter ordering.
template<int M, int DF, int COFF, bool TR>
__device__ __forceinline__ void stage1v(
    const float* __restrict__ verts,
    const float* __restrict__ pc,     // [3*M]
    const float* __restrict__ feat,   // [DF*M] (fallback gather)
    const float* __restrict__ featT,  // [M*DF] (transposed gather)
    float* __restrict__ out,
    int n, int lane)
{
    const float vx = verts[n*3+0], vy = verts[n*3+1], vz = verts[n*3+2];

    // seed: exact keys of points 0..7, sorted (Batcher 19-comparator network)
    u64 kk[8];
    {
#pragma unroll
        for (int q = 0; q < 8; ++q) {
            float dx=__fsub_rn(pc[q],vx), dy=__fsub_rn(pc[M+q],vy), dz=__fsub_rn(pc[2*M+q],vz);
            float d = __fmaf_rn(dz,dz,__fmaf_rn(dy,dy,__fmul_rn(dx,dx)));
            kk[q] = packkey(d, q);
        }
        cswap(kk[0],kk[1]); cswap(kk[2],kk[3]); cswap(kk[4],kk[5]); cswap(kk[6],kk[7]);
        cswap(kk[0],kk[2]); cswap(kk[1],kk[3]); cswap(kk[4],kk[6]); cswap(kk[5],kk[7]);
        cswap(kk[1],kk[2]); cswap(kk[5],kk[6]);
        cswap(kk[0],kk[4]); cswap(kk[1],kk[5]); cswap(kk[2],kk[6]); cswap(kk[3],kk[7]);
        cswap(kk[2],kk[4]); cswap(kk[3],kk[5]);
        cswap(kk[1],kk[2]); cswap(kk[3],kk[4]); cswap(kk[5],kk[6]);
    }
    float T = __uint_as_float((unsigned)(kk[7] >> 32));

    const float* __restrict__ px = pc;
    const float* __restrict__ py = pc + M;
    const float* __restrict__ pz = pc + 2*M;

    // 512-pt batches: lane owns points 8*lane .. 8*lane+7
    float4 Xa = *(const float4*)(px + 8*lane), Xb = *(const float4*)(px + 8*lane + 4);
    float4 Ya = *(const float4*)(py + 8*lane), Yb = *(const float4*)(py + 8*lane + 4);
    float4 Za = *(const float4*)(pz + 8*lane), Zb = *(const float4*)(pz + 8*lane + 4);
    for (int ob = 0; ob < M; ob += 512) {
        int nb = (ob + 512 < M) ? ob + 512 : 0;     // last prefetch dead
        float4 nXa = *(const float4*)(px + nb + 8*lane), nXb = *(const float4*)(px + nb + 8*lane + 4);
        float4 nYa = *(const float4*)(py + nb + 8*lane), nYb = *(const float4*)(py + nb + 8*lane + 4);
        float4 nZa = *(const float4*)(pz + nb + 8*lane), nZb = *(const float4*)(pz + nb + 8*lane + 4);
        float d0, d1, d2, d3, d4, d5, d6, d7;
        {
            float dx, dy, dz;
            dx=__fsub_rn(Xa.x,vx); dy=__fsub_rn(Ya.x,vy); dz=__fsub_rn(Za.x,vz);
            d0=__fmaf_rn(dz,dz,__fmaf_rn(dy,dy,__fmul_rn(dx,dx)));
            dx=__fsub_rn(Xa.y,vx); dy=__fsub_rn(Ya.y,vy); dz=__fsub_rn(Za.y,vz);
            d1=__fmaf_rn(dz,dz,__fmaf_rn(dy,dy,__fmul_rn(dx,dx)));
            dx=__fsub_rn(Xa.z,vx); dy=__fsub_rn(Ya.z,vy); dz=__fsub_rn(Za.z,vz);
            d2=__fmaf_rn(dz,dz,__fmaf_rn(dy,dy,__fmul_rn(dx,dx)));
            dx=__fsub_rn(Xa.w,vx); dy=__fsub_rn(Ya.w,vy); dz=__fsub_rn(Za.w,vz);
            d3=__fmaf_rn(dz,dz,__fmaf_rn(dy,dy,__fmul_rn(dx,dx)));
            dx=__fsub_rn(Xb.x,vx); dy=__fsub_rn(Yb.x,vy); dz=__fsub_rn(Zb.x,vz);
            d4=__fmaf_rn(dz,dz,__fmaf_rn(dy,dy,__fmul_rn(dx,dx)));
            dx=__fsub_rn(Xb.y,vx); dy=__fsub_rn(Yb.y,vy); dz=__fsub_rn(Zb.y,vz);
            d5=__fmaf_rn(dz,dz,__fmaf_rn(dy,dy,__fmul_rn(dx,dx)));
            dx=__fsub_rn(Xb.z,vx); dy=__fsub_rn(Yb.z,vy); dz=__fsub_rn(Zb.z,vz);
            d6=__fmaf_rn(dz,dz,__fmaf_rn(dy,dy,__fmul_rn(dx,dx)));
            dx=__fsub_rn(Xb.w,vx); dy=__fsub_rn(Yb.w,vy); dz=__fsub_rn(Zb.w,vz);
            d7=__fmaf_rn(dz,dz,__fmaf_rn(dy,dy,__fmul_rn(dx,dx)));
        }
        u64 m0 = __ballot(d0 <= T), m1 = __ballot(d1 <= T);
        u64 m2 = __ballot(d2 <= T), m3 = __ballot(d3 <= T);
        u64 m4 = __ballot(d4 <= T), m5 = __ballot(d5 <= T);
        u64 m6 = __ballot(d6 <= T), m7 = __ballot(d7 <= T);
        if (m0|m1|m2|m3|m4|m5|m6|m7) {              // wave-uniform rare path
            handle8(m0, d0, 0, ob, kk, T);
            handle8(m1, d1, 1, ob, kk, T);
            handle8(m2, d2, 2, ob, kk, T);
            handle8(m3, d3, 3, ob, kk, T);
            handle8(m4, d4, 4, ob, kk, T);
            handle8(m5, d5, 5, ob, kk, T);
            handle8(m6, d6, 6, ob, kk, T);
            handle8(m7, d7, 7, ob, kk, T);
        }
        Xa = nXa; Xb = nXb; Ya = nYa; Yb = nYb; Za = nZa; Zb = nZb;
    }

    // weights + feature mean, wave-local (no LDS)
    int m8[8]; float w8[8];
#pragma unroll
    for (int k = 0; k < 8; ++k) {
        int m = (int)(kk[k] & 0xFFFFFFFFu);
        m8[k] = m;
        w8[k] = wcalc<M>(pc, m, vx, vy, vz);
    }
    for (int f = lane; f < DF; f += 64) {
        float e[8];
#pragma unroll
        for (int k = 0; k < 8; ++k) {
            float fv = TR ? featT[m8[k]*DF + f] : feat[f*M + m8[k]];
            e[k] = __fmul_rn(w8[k], fv);
        }
        float s = __fadd_rn(__fadd_rn(__fadd_rn(e[0],e[1]), __fadd_rn(e[2],e[3])),
                            __fadd_rn(__fadd_rn(e[4],e[5]), __fadd_rn(e[6],e[7])));
        out[n*OSTRIDE + COFF + f] = __fmul_rn(0.125f, s);
    }
}

// LDS-tiled transpose: feat [Df, M] -> featT [M, Df]; BOTH sides coalesced.
// 64x64 tiles; 1536 blocks total (512 per stage).
__global__ __launch_bounds__(256)
void tr_kernel(const float* __restrict__ f1, const float* __restrict__ f2,
               const float* __restrict__ f3, float* __restrict__ ws)
{
    __shared__ float s[64][65];
    int b = blockIdx.x;
    const float* src; float* dst; int M, DF, tm, tf;
    if (b < 512)       { src = f1; dst = ws;           M = 32768; DF = 64;  tm = b & 511;        tf = b >> 9; }
    else if (b < 1024) { src = f2; dst = ws + 2097152; M = 16384; DF = 128; tm = (b-512) & 255;  tf = (b-512) >> 8; }
    else               { src = f3; dst = ws + 4194304; M = 8192;  DF = 256; tm = (b-1024) & 127; tf = (b-1024) >> 7; }
    const int mb = tm*64, fb = tf*64;
    const int tid = threadIdx.x;
    const int a0 = tid & 63, a1 = tid >> 6;
#pragma unroll
    for (int i = 0; i < 16; ++i) {                  // read: lanes along m
        int ff = a1 + i*4;
        s[ff][a0] = src[(fb+ff)*M + mb + a0];
    }
    __syncthreads();
#pragma unroll
    for (int i = 0; i < 16; ++i) {                  // write: lanes along f
        int mm2 = a1 + i*4;
        dst[(mb+mm2)*DF + fb + a0] = s[a0][mm2];
    }
}

// Grid: 1024 identical scan blocks (512 threads = 8 waves), one residency
// round at 4 blocks/CU: waves 0-3 (A) = stage1 for verts 4b..4b+3;
// waves 4-7 (B) = stage2 then stage3 for the same verts. A (32768 pts,
// ~66 events) ~ B (24576 pts, ~115 events + 2 seeds/emits) in issue count;
// each SIMD hosts an A/B mix so residual imbalance is absorbed by issue
// sharing, not tail. + 1 coord-copy block.
template<bool TR>
__global__ __launch_bounds__(NT, 8)
void gp_kernel(const float* __restrict__ verts,
               const float* __restrict__ pc1, const float* __restrict__ f1,
               const float* __restrict__ pc2, const float* __restrict__ f2,
               const float* __restrict__ pc3, const float* __restrict__ f3,
               const float* __restrict__ ws,
               float* __restrict__ out)
{
    int b = blockIdx.x;
    if (b < 1024) {
        const int lane = threadIdx.x & 63;
        const int wv   = threadIdx.x >> 6;          // 0..7
        const int n    = b*4 + (wv & 3);
        if (wv < 4) {
            stage1v<32768,  64,   3, TR>(verts, pc1, f1, ws,           out, n, lane);
        } else {
            stage1v<16384, 128,  67, TR>(verts, pc2, f2, ws + 2097152, out, n, lane);
            stage1v< 8192, 256, 195, TR>(verts, pc3, f3, ws + 4194304, out, n, lane);
        }
    } else {
        for (int i = threadIdx.x; i < NV*3; i += NT)
            out[(i/3)*OSTRIDE + (i % 3)] = verts[i];
    }
}

extern "C" void kernel_launch(void* const* d_in, const int* in_sizes, int n_in,
                              void* d_out, int out_size, void* d_ws, size_t ws_size,
                              hipStream_t stream) {
    const float* verts = (const float*)d_in[0];
    // d_in[1] = pc0_coords: unused (reference discards stage 0)
    const float* pc1 = (const float*)d_in[2];
    const float* f1  = (const float*)d_in[3];
    const float* pc2 = (const float*)d_in[4];
    const float* f2  = (const float*)d_in[5];
    const float* pc3 = (const float*)d_in[6];
    const float* f3  = (const float*)d_in[7];
    float* out = (float*)d_out;
    float* ws  = (float*)d_ws;

    if (ws_size >= 6291456u * sizeof(float)) {
        tr_kernel<<<1536, 256, 0, stream>>>(f1, f2, f3, ws);
        gp_kernel<true><<<1025, NT, 0, stream>>>(verts, pc1, f1, pc2, f2, pc3, f3, ws, out);
    } else {
        gp_kernel<false><<<1025, NT, 0, stream>>>(verts, pc1, f1, pc2, f2, pc3, f3, ws, out);
    }
}

// Round 11
// 172.179 us; speedup vs baseline: 1.5130x; 1.5130x over previous
//
#include <hip/hip_runtime.h>
#include <float.h>

#define NV 4096
#define OSTRIDE 451
#define NT 256
typedef unsigned long long u64;

// Sorted ascending top-8 insert, f32 key + idx payload. STRICT < placement:
// equal-key candidates go after existing entries, so processing candidates in
// ascending idx order reproduces top_k's stable tie semantics exactly.
// (PARTS=1: no cross-list merges anywhere, so no lex keys needed.)
__device__ __forceinline__ void ins8f(float (&dd)[8], int (&ii)[8], float cd, int cm) {
    bool b[7];
#pragma unroll
    for (int q = 0; q < 7; ++q) b[q] = cd < dd[q];
#pragma unroll
    for (int q = 7; q >= 1; --q) {
        bool hi = (q == 7) ? true : b[q];
        dd[q] = b[q-1] ? dd[q-1] : (hi ? cd : dd[q]);
        ii[q] = b[q-1] ? ii[q-1] : (hi ? cm : ii[q]);
    }
    dd[0] = b[0] ? cd : dd[0];
    ii[0] = b[0] ? cm : ii[0];
}

// wave-uniform event loop; ctz order = ascending lane = ascending idx within
// this mask (idx = ibase + lane). Refilter after each insert prunes storms.
__device__ __forceinline__ void handlef(u64 mask, float dj, int ibase,
                                        float (&dd)[8], int (&ii)[8], float& T) {
    while (mask) {
        int l = __builtin_ctzll(mask);
        mask &= mask - 1;
        int cm = ibase + l;
        if (cm < 8) continue;                      // seed points already in list
        float cd = __uint_as_float(__builtin_amdgcn_readlane(__float_as_uint(dj), l));
        if (cd < dd[7]) {
            ins8f(dd, ii, cd, cm);
            T = dd[7];
            mask &= __ballot(dj < T);              // refilter vs tightened T
        }
    }
}

// weight: reference recomputes dist2 from vec = nbr - vert, numpy op order
// (round products, sequential add, no fma), w = 1/(1+dist2)
template<int M>
__device__ __forceinline__ float wcalc(const float* __restrict__ pc, int m,
                                       float vx, float vy, float vz) {
    float qx = pc[m], qy = pc[M+m], qz = pc[2*M+m];
    float dx = __fsub_rn(qx, vx), dy = __fsub_rn(qy, vy), dz = __fsub_rn(qz, vz);
    float dist2 = __fadd_rn(__fadd_rn(__fmul_rn(dx,dx), __fmul_rn(dy,dy)),
                            __fmul_rn(dz,dz));
    return __fdiv_rn(1.0f, __fadd_rn(1.0f, dist2));
}

// One wave owns 4 vertices, full scan of one stage (PARTS=1: minimal events,
// no merges, no LDS, no barriers). 256-pt batches: lane l handles idx
// ob+64j+l for j=0..3 (coalesced dword loads; j-major event processing stays
// globally idx-ascending -> exact tie semantics). 12 loads prefetched 1 batch
// ahead; compute window ~250cy matches L2 latency. Selection distance =
// direct form (p-v).(p-v): abs err ~ulp(d2), ~500x tighter than the
// reference's cancellation form -> matches the f64-arbiter ordering.
template<int M, int DF, int COFF, bool TR>
__device__ __forceinline__ void stage4v(
    const float* __restrict__ verts,
    const float* __restrict__ pc,     // [3*M]
    const float* __restrict__ feat,   // [DF*M] (fallback gather)
    const float* __restrict__ featT,  // [M*DF] (transposed gather)
    float* __restrict__ out,
    int vbase, int lane)
{
    float vx[4], vy[4], vz[4];
#pragma unroll
    for (int u = 0; u < 4; ++u) {
        vx[u] = verts[(vbase+u)*3+0];
        vy[u] = verts[(vbase+u)*3+1];
        vz[u] = verts[(vbase+u)*3+2];
    }

    float dd[4][8]; int ii[4][8];
#pragma unroll
    for (int u = 0; u < 4; ++u)
#pragma unroll
        for (int q = 0; q < 8; ++q) { dd[u][q] = FLT_MAX; ii[u][q] = 0x7fffffff; }

    // seed: points 0..7 inserted in ascending idx order (stable by construction)
#pragma unroll
    for (int q = 0; q < 8; ++q) {
        float sx = pc[q], sy = pc[M+q], sz = pc[2*M+q];
#pragma unroll
        for (int u = 0; u < 4; ++u) {
            float dx=__fsub_rn(sx,vx[u]), dy=__fsub_rn(sy,vy[u]), dz=__fsub_rn(sz,vz[u]);
            float d = __fmaf_rn(dz,dz,__fmaf_rn(dy,dy,__fmul_rn(dx,dx)));
            ins8f(dd[u], ii[u], d, q);   // dd[7]=FLT_MAX until 8 inserted
        }
    }
    float T[4];
#pragma unroll
    for (int u = 0; u < 4; ++u) T[u] = dd[u][7];

    const float* __restrict__ px = pc;
    const float* __restrict__ py = pc + M;
    const float* __restrict__ pz = pc + 2*M;

    // preload batch 0
    float cx[4], cy[4], cz[4];
#pragma unroll
    for (int j = 0; j < 4; ++j) {
        cx[j] = px[64*j + lane]; cy[j] = py[64*j + lane]; cz[j] = pz[64*j + lane];
    }

    for (int ob = 0; ob < M; ob += 256) {
        int nb = (ob + 256 < M) ? ob + 256 : 0;    // last prefetch dead
        float nx[4], ny[4], nz[4];
#pragma unroll
        for (int j = 0; j < 4; ++j) {
            nx[j] = px[nb + 64*j + lane];
            ny[j] = py[nb + 64*j + lane];
            nz[j] = pz[nb + 64*j + lane];
        }
        float d[4][4];
#pragma unroll
        for (int u = 0; u < 4; ++u)
#pragma unroll
            for (int j = 0; j < 4; ++j) {
                float dx = __fsub_rn(cx[j], vx[u]);
                float dy = __fsub_rn(cy[j], vy[u]);
                float dz = __fsub_rn(cz[j], vz[u]);
                d[u][j] = __fmaf_rn(dz,dz,__fmaf_rn(dy,dy,__fmul_rn(dx,dx)));
            }
        u64 msk[4][4]; u64 any = 0;
#pragma unroll
        for (int u = 0; u < 4; ++u)
#pragma unroll
            for (int j = 0; j < 4; ++j) {
                msk[u][j] = __ballot(d[u][j] < T[u]);   // strict <: ties rejected
                any |= msk[u][j];
            }
        if (any) {                                  // wave-uniform rare path
#pragma unroll
            for (int u = 0; u < 4; ++u)
#pragma unroll
                for (int j = 0; j < 4; ++j)         // j ascending = idx ascending
                    handlef(msk[u][j], d[u][j], ob + 64*j, dd[u], ii[u], T[u]);
        }
#pragma unroll
        for (int j = 0; j < 4; ++j) { cx[j]=nx[j]; cy[j]=ny[j]; cz[j]=nz[j]; }
    }

    // weights + feature mean, wave-local (no LDS)
#pragma unroll
    for (int u = 0; u < 4; ++u) {
        int m8[8]; float w8[8];
#pragma unroll
        for (int k = 0; k < 8; ++k) {
            int m = ii[u][k];
            m8[k] = m;
            w8[k] = wcalc<M>(pc, m, vx[u], vy[u], vz[u]);
        }
        const int n = vbase + u;
        for (int f = lane; f < DF; f += 64) {
            float e[8];
#pragma unroll
            for (int k = 0; k < 8; ++k) {
                float fv = TR ? featT[m8[k]*DF + f] : feat[f*M + m8[k]];
                e[k] = __fmul_rn(w8[k], fv);
            }
            float s = __fadd_rn(__fadd_rn(__fadd_rn(e[0],e[1]), __fadd_rn(e[2],e[3])),
                                __fadd_rn(__fadd_rn(e[4],e[5]), __fadd_rn(e[6],e[7])));
            out[n*OSTRIDE + COFF + f] = __fmul_rn(0.125f, s);
        }
    }
}

// LDS-tiled transpose: feat [Df, M] -> featT [M, Df]; BOTH sides coalesced.
// 64x64 tiles; 1536 blocks total (512 per stage).
__global__ __launch_bounds__(256)
void tr_kernel(const float* __restrict__ f1, const float* __restrict__ f2,
               const float* __restrict__ f3, float* __restrict__ ws)
{
    __shared__ float s[64][65];
    int b = blockIdx.x;
    const float* src; float* dst; int M, DF, tm, tf;
    if (b < 512)       { src = f1; dst = ws;           M = 32768; DF = 64;  tm = b & 511;        tf = b >> 9; }
    else if (b < 1024) { src = f2; dst = ws + 2097152; M = 16384; DF = 128; tm = (b-512) & 255;  tf = (b-512) >> 8; }
    else               { src = f3; dst = ws + 4194304; M = 8192;  DF = 256; tm = (b-1024) & 127; tf = (b-1024) >> 7; }
    const int mb = tm*64, fb = tf*64;
    const int tid = threadIdx.x;
    const int a0 = tid & 63, a1 = tid >> 6;
#pragma unroll
    for (int i = 0; i < 16; ++i) {                  // read: lanes along m
        int ff = a1 + i*4;
        s[ff][a0] = src[(fb+ff)*M + mb + a0];
    }
    __syncthreads();
#pragma unroll
    for (int i = 0; i < 16; ++i) {                  // write: lanes along f
        int mm2 = a1 + i*4;
        dst[(mb+mm2)*DF + fb + a0] = s[a0][mm2];
    }
}

// Grid (R5's winning shape): 769 blocks x 4 waves, U=4 verts/wave, one stage
// per block: b<256 stage1, b<512 stage2, b<768 stage3, b=768 coord-copy.
template<bool TR>
__global__ __launch_bounds__(NT, 3)
void gp_kernel(const float* __restrict__ verts,
               const float* __restrict__ pc1, const float* __restrict__ f1,
               const float* __restrict__ pc2, const float* __restrict__ f2,
               const float* __restrict__ pc3, const float* __restrict__ f3,
               const float* __restrict__ ws,
               float* __restrict__ out)
{
    int b = blockIdx.x;
    if (b < 768) {
        const int lane = threadIdx.x & 63;
        const int wv   = threadIdx.x >> 6;
        if (b < 256) {
            stage4v<32768,  64,   3, TR>(verts, pc1, f1, ws,           out, (b*4 + wv)*4, lane);
        } else if (b < 512) {
            stage4v<16384, 128,  67, TR>(verts, pc2, f2, ws + 2097152, out, ((b-256)*4 + wv)*4, lane);
        } else {
            stage4v< 8192, 256, 195, TR>(verts, pc3, f3, ws + 4194304, out, ((b-512)*4 + wv)*4, lane);
        }
    } else {
        for (int i = threadIdx.x; i < NV*3; i += NT)
            out[(i/3)*OSTRIDE + (i % 3)] = verts[i];
    }
}

extern "C" void kernel_launch(void* const* d_in, const int* in_sizes, int n_in,
                              void* d_out, int out_size, void* d_ws, size_t ws_size,
                              hipStream_t stream) {
    const float* verts = (const float*)d_in[0];
    // d_in[1] = pc0_coords: unused (reference discards stage 0)
    const float* pc1 = (const float*)d_in[2];
    const float* f1  = (const float*)d_in[3];
    const float* pc2 = (const float*)d_in[4];
    const float* f2  = (const float*)d_in[5];
    const float* pc3 = (const float*)d_in[6];
    const float* f3  = (const float*)d_in[7];
    float* out = (float*)d_out;
    float* ws  = (float*)d_ws;

    if (ws_size >= 6291456u * sizeof(float)) {
        tr_kernel<<<1536, 256, 0, stream>>>(f1, f2, f3, ws);
        gp_kernel<true><<<769, NT, 0, stream>>>(verts, pc1, f1, pc2, f2, pc3, f3, ws, out);
    } else {
        gp_kernel<false><<<769, NT, 0, stream>>>(verts, pc1, f1, pc2, f2, pc3, f3, ws, out);
    }
}

// Round 12
// 162.000 us; speedup vs baseline: 1.6080x; 1.0628x over previous
//
#include <hip/hip_runtime.h>
#include <float.h>

#define NV 4096
#define OSTRIDE 451
#define NT 256
typedef unsigned long long u64;

// Sorted ascending top-8 insert, f32 key + idx payload. STRICT < placement:
// equal-key candidates go after existing entries, so processing candidates in
// ascending idx order reproduces top_k's stable tie semantics exactly.
// (PARTS=1: no cross-list merges anywhere, so no lex keys needed.)
__device__ __forceinline__ void ins8f(float (&dd)[8], int (&ii)[8], float cd, int cm) {
    bool b[7];
#pragma unroll
    for (int q = 0; q < 7; ++q) b[q] = cd < dd[q];
#pragma unroll
    for (int q = 7; q >= 1; --q) {
        bool hi = (q == 7) ? true : b[q];
        dd[q] = b[q-1] ? dd[q-1] : (hi ? cd : dd[q]);
        ii[q] = b[q-1] ? ii[q-1] : (hi ? cm : ii[q]);
    }
    dd[0] = b[0] ? cd : dd[0];
    ii[0] = b[0] ? cm : ii[0];
}

// wave-uniform event loop; ctz order = ascending lane = ascending idx within
// this mask (idx = ibase + lane). Refilter after each insert prunes storms.
__device__ __forceinline__ void handlef(u64 mask, float dj, int ibase,
                                        float (&dd)[8], int (&ii)[8], float& T) {
    while (mask) {
        int l = __builtin_ctzll(mask);
        mask &= mask - 1;
        int cm = ibase + l;
        if (cm < 8) continue;                      // seed points already in list
        float cd = __uint_as_float(__builtin_amdgcn_readlane(__float_as_uint(dj), l));
        if (cd < dd[7]) {
            ins8f(dd, ii, cd, cm);
            T = dd[7];
            mask &= __ballot(dj < T);              // refilter vs tightened T
        }
    }
}

// weight: reference recomputes dist2 from vec = nbr - vert, numpy op order
// (round products, sequential add, no fma), w = 1/(1+dist2)
template<int M>
__device__ __forceinline__ float wcalc(const float* __restrict__ pc, int m,
                                       float vx, float vy, float vz) {
    float qx = pc[m], qy = pc[M+m], qz = pc[2*M+m];
    float dx = __fsub_rn(qx, vx), dy = __fsub_rn(qy, vy), dz = __fsub_rn(qz, vz);
    float dist2 = __fadd_rn(__fadd_rn(__fmul_rn(dx,dx), __fmul_rn(dy,dy)),
                            __fmul_rn(dz,dz));
    return __fdiv_rn(1.0f, __fadd_rn(1.0f, dist2));
}

// One wave owns 2 vertices, full scan of one stage (PARTS=1: minimal events,
// no merges, no LDS, no barriers). 256-pt batches: lane l handles idx
// ob+64j+l for j=0..3 (coalesced dword loads; j-major event processing stays
// globally idx-ascending -> exact tie semantics). 12 loads prefetched 1 batch
// ahead. Selection distance = direct form (p-v).(p-v): abs err ~ulp(d2),
// ~500x tighter than the reference's cancellation form -> matches the
// f64-arbiter ordering.
template<int M, int DF, int COFF, bool TR>
__device__ __forceinline__ void stage2v(
    const float* __restrict__ verts,
    const float* __restrict__ pc,     // [3*M]
    const float* __restrict__ feat,   // [DF*M] (fallback gather)
    const float* __restrict__ featT,  // [M*DF] (transposed gather)
    float* __restrict__ out,
    int vbase, int lane)
{
    float vx[2], vy[2], vz[2];
#pragma unroll
    for (int u = 0; u < 2; ++u) {
        vx[u] = verts[(vbase+u)*3+0];
        vy[u] = verts[(vbase+u)*3+1];
        vz[u] = verts[(vbase+u)*3+2];
    }

    float dd[2][8]; int ii[2][8];
#pragma unroll
    for (int u = 0; u < 2; ++u)
#pragma unroll
        for (int q = 0; q < 8; ++q) { dd[u][q] = FLT_MAX; ii[u][q] = 0x7fffffff; }

    // seed: points 0..7 inserted in ascending idx order (stable by construction)
#pragma unroll
    for (int q = 0; q < 8; ++q) {
        float sx = pc[q], sy = pc[M+q], sz = pc[2*M+q];
#pragma unroll
        for (int u = 0; u < 2; ++u) {
            float dx=__fsub_rn(sx,vx[u]), dy=__fsub_rn(sy,vy[u]), dz=__fsub_rn(sz,vz[u]);
            float d = __fmaf_rn(dz,dz,__fmaf_rn(dy,dy,__fmul_rn(dx,dx)));
            ins8f(dd[u], ii[u], d, q);   // dd[7]=FLT_MAX until 8 inserted
        }
    }
    float T[2];
#pragma unroll
    for (int u = 0; u < 2; ++u) T[u] = dd[u][7];

    const float* __restrict__ px = pc;
    const float* __restrict__ py = pc + M;
    const float* __restrict__ pz = pc + 2*M;

    // preload batch 0
    float cx[4], cy[4], cz[4];
#pragma unroll
    for (int j = 0; j < 4; ++j) {
        cx[j] = px[64*j + lane]; cy[j] = py[64*j + lane]; cz[j] = pz[64*j + lane];
    }

    for (int ob = 0; ob < M; ob += 256) {
        int nb = (ob + 256 < M) ? ob + 256 : 0;    // last prefetch dead
        float nx[4], ny[4], nz[4];
#pragma unroll
        for (int j = 0; j < 4; ++j) {
            nx[j] = px[nb + 64*j + lane];
            ny[j] = py[nb + 64*j + lane];
            nz[j] = pz[nb + 64*j + lane];
        }
        float d[2][4];
#pragma unroll
        for (int u = 0; u < 2; ++u)
#pragma unroll
            for (int j = 0; j < 4; ++j) {
                float dx = __fsub_rn(cx[j], vx[u]);
                float dy = __fsub_rn(cy[j], vy[u]);
                float dz = __fsub_rn(cz[j], vz[u]);
                d[u][j] = __fmaf_rn(dz,dz,__fmaf_rn(dy,dy,__fmul_rn(dx,dx)));
            }
        u64 msk[2][4]; u64 any = 0;
#pragma unroll
        for (int u = 0; u < 2; ++u)
#pragma unroll
            for (int j = 0; j < 4; ++j) {
                msk[u][j] = __ballot(d[u][j] < T[u]);   // strict <: ties rejected
                any |= msk[u][j];
            }
        if (any) {                                  // wave-uniform rare path
#pragma unroll
            for (int u = 0; u < 2; ++u)
#pragma unroll
                for (int j = 0; j < 4; ++j)         // j ascending = idx ascending
                    handlef(msk[u][j], d[u][j], ob + 64*j, dd[u], ii[u], T[u]);
        }
#pragma unroll
        for (int j = 0; j < 4; ++j) { cx[j]=nx[j]; cy[j]=ny[j]; cz[j]=nz[j]; }
    }

    // weights + feature mean, wave-local (no LDS)
#pragma unroll
    for (int u = 0; u < 2; ++u) {
        int m8[8]; float w8[8];
#pragma unroll
        for (int k = 0; k < 8; ++k) {
            int m = ii[u][k];
            m8[k] = m;
            w8[k] = wcalc<M>(pc, m, vx[u], vy[u], vz[u]);
        }
        const int n = vbase + u;
        for (int f = lane; f < DF; f += 64) {
            float e[8];
#pragma unroll
            for (int k = 0; k < 8; ++k) {
                float fv = TR ? featT[m8[k]*DF + f] : feat[f*M + m8[k]];
                e[k] = __fmul_rn(w8[k], fv);
            }
            float s = __fadd_rn(__fadd_rn(__fadd_rn(e[0],e[1]), __fadd_rn(e[2],e[3])),
                                __fadd_rn(__fadd_rn(e[4],e[5]), __fadd_rn(e[6],e[7])));
            out[n*OSTRIDE + COFF + f] = __fmul_rn(0.125f, s);
        }
    }
}

// LDS-tiled transpose: feat [Df, M] -> featT [M, Df]; BOTH sides coalesced.
// 64x64 tiles; 1536 blocks total (512 per stage).
__global__ __launch_bounds__(256)
void tr_kernel(const float* __restrict__ f1, const float* __restrict__ f2,
               const float* __restrict__ f3, float* __restrict__ ws)
{
    __shared__ float s[64][65];
    int b = blockIdx.x;
    const float* src; float* dst; int M, DF, tm, tf;
    if (b < 512)       { src = f1; dst = ws;           M = 32768; DF = 64;  tm = b & 511;        tf = b >> 9; }
    else if (b < 1024) { src = f2; dst = ws + 2097152; M = 16384; DF = 128; tm = (b-512) & 255;  tf = (b-512) >> 8; }
    else               { src = f3; dst = ws + 4194304; M = 8192;  DF = 256; tm = (b-1024) & 127; tf = (b-1024) >> 7; }
    const int mb = tm*64, fb = tf*64;
    const int tid = threadIdx.x;
    const int a0 = tid & 63, a1 = tid >> 6;
#pragma unroll
    for (int i = 0; i < 16; ++i) {                  // read: lanes along m
        int ff = a1 + i*4;
        s[ff][a0] = src[(fb+ff)*M + mb + a0];
    }
    __syncthreads();
#pragma unroll
    for (int i = 0; i < 16; ++i) {                  // write: lanes along f
        int mm2 = a1 + i*4;
        dst[(mb+mm2)*DF + fb + a0] = s[a0][mm2];
    }
}

// Grid: 1537 blocks x 4 waves, U=2 verts/wave, one stage per block:
// b<512 stage1, b<1024 stage2, b<1536 stage3, b=1536 coord-copy.
// 6144 scan waves = exactly one residency round at 6 blocks/CU; round-robin
// dispatch gives each CU {2x s1, 2x s2, 2x s3} = equal total work.
template<bool TR>
__global__ __launch_bounds__(NT, 6)
void gp_kernel(const float* __restrict__ verts,
               const float* __restrict__ pc1, const float* __restrict__ f1,
               const float* __restrict__ pc2, const float* __restrict__ f2,
               const float* __restrict__ pc3, const float* __restrict__ f3,
               const float* __restrict__ ws,
               float* __restrict__ out)
{
    int b = blockIdx.x;
    if (b < 1536) {
        const int lane = threadIdx.x & 63;
        const int wv   = threadIdx.x >> 6;
        if (b < 512) {
            stage2v<32768,  64,   3, TR>(verts, pc1, f1, ws,           out, (b*4 + wv)*2, lane);
        } else if (b < 1024) {
            stage2v<16384, 128,  67, TR>(verts, pc2, f2, ws + 2097152, out, ((b-512)*4 + wv)*2, lane);
        } else {
            stage2v< 8192, 256, 195, TR>(verts, pc3, f3, ws + 4194304, out, ((b-1024)*4 + wv)*2, lane);
        }
    } else {
        for (int i = threadIdx.x; i < NV*3; i += NT)
            out[(i/3)*OSTRIDE + (i % 3)] = verts[i];
    }
}

extern "C" void kernel_launch(void* const* d_in, const int* in_sizes, int n_in,
                              void* d_out, int out_size, void* d_ws, size_t ws_size,
                              hipStream_t stream) {
    const float* verts = (const float*)d_in[0];
    // d_in[1] = pc0_coords: unused (reference discards stage 0)
    const float* pc1 = (const float*)d_in[2];
    const float* f1  = (const float*)d_in[3];
    const float* pc2 = (const float*)d_in[4];
    const float* f2  = (const float*)d_in[5];
    const float* pc3 = (const float*)d_in[6];
    const float* f3  = (const float*)d_in[7];
    float* out = (float*)d_out;
    float* ws  = (float*)d_ws;

    if (ws_size >= 6291456u * sizeof(float)) {
        tr_kernel<<<1536, 256, 0, stream>>>(f1, f2, f3, ws);
        gp_kernel<true><<<1537, NT, 0, stream>>>(verts, pc1, f1, pc2, f2, pc3, f3, ws, out);
    } else {
        gp_kernel<false><<<1537, NT, 0, stream>>>(verts, pc1, f1, pc2, f2, pc3, f3, ws, out);
    }
}

// Round 13
// 131.107 us; speedup vs baseline: 1.9870x; 1.2356x over previous
//
#include <hip/hip_runtime.h>
#include <float.h>

#define NV 4096
#define OSTRIDE 451
#define NT 256
typedef unsigned long long u64;

// Wave-uniform top-8 list held as f32 BIT PATTERNS (u32) + idx, kept in
// SGPRs: d2 >= 0 so u32 compare == f32 compare. All inserts are uniform
// u32 ternaries -> SALU (s_cmp/s_cselect), freeing the VALU pipe.
struct Top8 {
    unsigned d0,d1,d2,d3,d4,d5,d6,d7;   // ascending
    int      i0,i1,i2,i3,i4,i5,i6,i7;
};

__device__ __forceinline__ void top8_init(Top8& t) {
    t.d0=t.d1=t.d2=t.d3=t.d4=t.d5=t.d6=t.d7=0x7F7FFFFFu;  // FLT_MAX bits
    t.i0=t.i1=t.i2=t.i3=t.i4=t.i5=t.i6=t.i7=0x7fffffff;
}

// sorted ascending insert (caller guarantees cd < t.d7); STRICT < placement:
// equal-key candidates go after existing entries, so ascending-idx processing
// reproduces top_k's stable tie semantics exactly. (PARTS=1: no merges.)
__device__ __forceinline__ void ins8s(Top8& t, unsigned cd, int cm) {
    bool b0 = cd < t.d0, b1 = cd < t.d1, b2 = cd < t.d2, b3 = cd < t.d3;
    bool b4 = cd < t.d4, b5 = cd < t.d5, b6 = cd < t.d6;
    t.d7 = b6 ? t.d6 : cd;                 t.i7 = b6 ? t.i6 : cm;
    t.d6 = b5 ? t.d5 : (b6 ? cd : t.d6);   t.i6 = b5 ? t.i5 : (b6 ? cm : t.i6);
    t.d5 = b4 ? t.d4 : (b5 ? cd : t.d5);   t.i5 = b4 ? t.i4 : (b5 ? cm : t.i5);
    t.d4 = b3 ? t.d3 : (b4 ? cd : t.d4);   t.i4 = b3 ? t.i3 : (b4 ? cm : t.i4);
    t.d3 = b2 ? t.d2 : (b3 ? cd : t.d3);   t.i3 = b2 ? t.i2 : (b3 ? cm : t.i3);
    t.d2 = b1 ? t.d1 : (b2 ? cd : t.d2);   t.i2 = b1 ? t.i1 : (b2 ? cm : t.i2);
    t.d1 = b0 ? t.d0 : (b1 ? cd : t.d1);   t.i1 = b0 ? t.i0 : (b1 ? cm : t.i1);
    t.d0 = b0 ? cd : t.d0;                 t.i0 = b0 ? cm : t.i0;
}

// wave-uniform event loop; ctz order = ascending lane = ascending idx within
// this mask (idx = ibase + lane). Refilter after each insert prunes storms.
// Only VALU per event: 1 readlane + 1 refilter v_cmp; rest is SALU.
__device__ __forceinline__ void handle_s(u64 mask, float dj, int ibase,
                                         Top8& t, float& Tf) {
    while (mask) {
        int l = __builtin_ctzll(mask);
        mask &= mask - 1;
        int cm = ibase + l;
        if (cm < 8) continue;                      // seed points already in list
        unsigned cd = (unsigned)__builtin_amdgcn_readlane(__float_as_uint(dj), l);
        if (cd < t.d7) {
            ins8s(t, cd, cm);
            Tf = __uint_as_float(t.d7);
            mask &= __ballot(dj < Tf);             // refilter vs tightened T
        }
    }
}

// weight: reference recomputes dist2 from vec = nbr - vert, numpy op order
// (round products, sequential add, no fma), w = 1/(1+dist2)
template<int M>
__device__ __forceinline__ float wcalc(const float* __restrict__ pc, int m,
                                       float vx, float vy, float vz) {
    float qx = pc[m], qy = pc[M+m], qz = pc[2*M+m];
    float dx = __fsub_rn(qx, vx), dy = __fsub_rn(qy, vy), dz = __fsub_rn(qz, vz);
    float dist2 = __fadd_rn(__fadd_rn(__fmul_rn(dx,dx), __fmul_rn(dy,dy)),
                            __fmul_rn(dz,dz));
    return __fdiv_rn(1.0f, __fadd_rn(1.0f, dist2));
}

// One wave owns 2 vertices, full scan of one stage (PARTS=1: minimal events,
// no merges, no LDS, no barriers). 256-pt batches: lane l handles idx
// ob+64j+l for j=0..3 (coalesced dword loads; j-major event processing stays
// globally idx-ascending -> exact tie semantics). Selection distance = direct
// form (p-v).(p-v): abs err ~ulp(d2), ~500x tighter than the reference's
// cancellation form -> matches the f64-arbiter ordering.
template<int M, int DF, int COFF, bool TR>
__device__ __forceinline__ void stage2v(
    const float* __restrict__ verts,
    const float* __restrict__ pc,     // [3*M]
    const float* __restrict__ feat,   // [DF*M] (fallback gather)
    const float* __restrict__ featT,  // [M*DF] (transposed gather)
    float* __restrict__ out,
    int vbase, int lane)
{
    float vx[2], vy[2], vz[2];
#pragma unroll
    for (int u = 0; u < 2; ++u) {
        vx[u] = verts[(vbase+u)*3+0];
        vy[u] = verts[(vbase+u)*3+1];
        vz[u] = verts[(vbase+u)*3+2];
    }

    Top8 t0, t1;
    top8_init(t0); top8_init(t1);

    // seed: points 0..7 in ascending idx order (value uniform across lanes;
    // readfirstlane moves it to SGPR, insert is SALU)
#pragma unroll
    for (int q = 0; q < 8; ++q) {
        float sx = pc[q], sy = pc[M+q], sz = pc[2*M+q];
        {
            float dx=__fsub_rn(sx,vx[0]), dy=__fsub_rn(sy,vy[0]), dz=__fsub_rn(sz,vz[0]);
            float d = __fmaf_rn(dz,dz,__fmaf_rn(dy,dy,__fmul_rn(dx,dx)));
            unsigned cd = (unsigned)__builtin_amdgcn_readfirstlane(__float_as_uint(d));
            if (cd < t0.d7) ins8s(t0, cd, q);
        }
        {
            float dx=__fsub_rn(sx,vx[1]), dy=__fsub_rn(sy,vy[1]), dz=__fsub_rn(sz,vz[1]);
            float d = __fmaf_rn(dz,dz,__fmaf_rn(dy,dy,__fmul_rn(dx,dx)));
            unsigned cd = (unsigned)__builtin_amdgcn_readfirstlane(__float_as_uint(d));
            if (cd < t1.d7) ins8s(t1, cd, q);
        }
    }
    float T[2];
    T[0] = __uint_as_float(t0.d7);
    T[1] = __uint_as_float(t1.d7);

    const float* __restrict__ px = pc;
    const float* __restrict__ py = pc + M;
    const float* __restrict__ pz = pc + 2*M;

    // preload batch 0
    float cx[4], cy[4], cz[4];
#pragma unroll
    for (int j = 0; j < 4; ++j) {
        cx[j] = px[64*j + lane]; cy[j] = py[64*j + lane]; cz[j] = pz[64*j + lane];
    }

    for (int ob = 0; ob < M; ob += 256) {
        int nb = (ob + 256 < M) ? ob + 256 : 0;    // last prefetch dead
        float nx[4], ny[4], nz[4];
#pragma unroll
        for (int j = 0; j < 4; ++j) {
            nx[j] = px[nb + 64*j + lane];
            ny[j] = py[nb + 64*j + lane];
            nz[j] = pz[nb + 64*j + lane];
        }
        float d[2][4];
#pragma unroll
        for (int u = 0; u < 2; ++u)
#pragma unroll
            for (int j = 0; j < 4; ++j) {
                float dx = __fsub_rn(cx[j], vx[u]);
                float dy = __fsub_rn(cy[j], vy[u]);
                float dz = __fsub_rn(cz[j], vz[u]);
                d[u][j] = __fmaf_rn(dz,dz,__fmaf_rn(dy,dy,__fmul_rn(dx,dx)));
            }
        u64 msk[2][4]; u64 any = 0;
#pragma unroll
        for (int u = 0; u < 2; ++u)
#pragma unroll
            for (int j = 0; j < 4; ++j) {
                msk[u][j] = __ballot(d[u][j] < T[u]);   // strict <: ties rejected
                any |= msk[u][j];
            }
        if (any) {                                  // wave-uniform rare path
#pragma unroll
            for (int j = 0; j < 4; ++j)             // j ascending = idx ascending
                handle_s(msk[0][j], d[0][j], ob + 64*j, t0, T[0]);
#pragma unroll
            for (int j = 0; j < 4; ++j)
                handle_s(msk[1][j], d[1][j], ob + 64*j, t1, T[1]);
        }
#pragma unroll
        for (int j = 0; j < 4; ++j) { cx[j]=nx[j]; cy[j]=ny[j]; cz[j]=nz[j]; }
    }

    // weights + feature mean, wave-local (no LDS)
    int m8[2][8];
    m8[0][0]=t0.i0; m8[0][1]=t0.i1; m8[0][2]=t0.i2; m8[0][3]=t0.i3;
    m8[0][4]=t0.i4; m8[0][5]=t0.i5; m8[0][6]=t0.i6; m8[0][7]=t0.i7;
    m8[1][0]=t1.i0; m8[1][1]=t1.i1; m8[1][2]=t1.i2; m8[1][3]=t1.i3;
    m8[1][4]=t1.i4; m8[1][5]=t1.i5; m8[1][6]=t1.i6; m8[1][7]=t1.i7;
#pragma unroll
    for (int u = 0; u < 2; ++u) {
        float w8[8];
#pragma unroll
        for (int k = 0; k < 8; ++k)
            w8[k] = wcalc<M>(pc, m8[u][k], vx[u], vy[u], vz[u]);
        const int n = vbase + u;
        for (int f = lane; f < DF; f += 64) {
            float e[8];
#pragma unroll
            for (int k = 0; k < 8; ++k) {
                float fv = TR ? featT[m8[u][k]*DF + f] : feat[f*M + m8[u][k]];
                e[k] = __fmul_rn(w8[k], fv);
            }
            float s = __fadd_rn(__fadd_rn(__fadd_rn(e[0],e[1]), __fadd_rn(e[2],e[3])),
                                __fadd_rn(__fadd_rn(e[4],e[5]), __fadd_rn(e[6],e[7])));
            out[n*OSTRIDE + COFF + f] = __fmul_rn(0.125f, s);
        }
    }
}

// LDS-tiled transpose: feat [Df, M] -> featT [M, Df]; BOTH sides coalesced.
// 64x64 tiles; 1536 blocks total (512 per stage).
__global__ __launch_bounds__(256)
void tr_kernel(const float* __restrict__ f1, const float* __restrict__ f2,
               const float* __restrict__ f3, float* __restrict__ ws)
{
    __shared__ float s[64][65];
    int b = blockIdx.x;
    const float* src; float* dst; int M, DF, tm, tf;
    if (b < 512)       { src = f1; dst = ws;           M = 32768; DF = 64;  tm = b & 511;        tf = b >> 9; }
    else if (b < 1024) { src = f2; dst = ws + 2097152; M = 16384; DF = 128; tm = (b-512) & 255;  tf = (b-512) >> 8; }
    else               { src = f3; dst = ws + 4194304; M = 8192;  DF = 256; tm = (b-1024) & 127; tf = (b-1024) >> 7; }
    const int mb = tm*64, fb = tf*64;
    const int tid = threadIdx.x;
    const int a0 = tid & 63, a1 = tid >> 6;
#pragma unroll
    for (int i = 0; i < 16; ++i) {                  // read: lanes along m
        int ff = a1 + i*4;
        s[ff][a0] = src[(fb+ff)*M + mb + a0];
    }
    __syncthreads();
#pragma unroll
    for (int i = 0; i < 16; ++i) {                  // write: lanes along f
        int mm2 = a1 + i*4;
        dst[(mb+mm2)*DF + fb + a0] = s[a0][mm2];
    }
}

// Grid (R12 winner): 1537 blocks x 4 waves, U=2 verts/wave, one stage per
// block: b<512 stage1, b<1024 stage2, b<1536 stage3, b=1536 coord-copy.
// 6144 scan waves = one residency round at 6 blocks/CU; round-robin dispatch
// gives each CU {2x s1, 2x s2, 2x s3} = equal total work.
template<bool TR>
__global__ __launch_bounds__(NT, 6)
void gp_kernel(const float* __restrict__ verts,
               const float* __restrict__ pc1, const float* __restrict__ f1,
               const float* __restrict__ pc2, const float* __restrict__ f2,
               const float* __restrict__ pc3, const float* __restrict__ f3,
               const float* __restrict__ ws,
               float* __restrict__ out)
{
    int b = blockIdx.x;
    if (b < 1536) {
        const int lane = threadIdx.x & 63;
        const int wv   = threadIdx.x >> 6;
        if (b < 512) {
            stage2v<32768,  64,   3, TR>(verts, pc1, f1, ws,           out, (b*4 + wv)*2, lane);
        } else if (b < 1024) {
            stage2v<16384, 128,  67, TR>(verts, pc2, f2, ws + 2097152, out, ((b-512)*4 + wv)*2, lane);
        } else {
            stage2v< 8192, 256, 195, TR>(verts, pc3, f3, ws + 4194304, out, ((b-1024)*4 + wv)*2, lane);
        }
    } else {
        for (int i = threadIdx.x; i < NV*3; i += NT)
            out[(i/3)*OSTRIDE + (i % 3)] = verts[i];
    }
}

extern "C" void kernel_launch(void* const* d_in, const int* in_sizes, int n_in,
                              void* d_out, int out_size, void* d_ws, size_t ws_size,
                              hipStream_t stream) {
    const float* verts = (const float*)d_in[0];
    // d_in[1] = pc0_coords: unused (reference discards stage 0)
    const float* pc1 = (const float*)d_in[2];
    const float* f1  = (const float*)d_in[3];
    const float* pc2 = (const float*)d_in[4];
    const float* f2  = (const float*)d_in[5];
    const float* pc3 = (const float*)d_in[6];
    const float* f3  = (const float*)d_in[7];
    float* out = (float*)d_out;
    float* ws  = (float*)d_ws;

    if (ws_size >= 6291456u * sizeof(float)) {
        tr_kernel<<<1536, 256, 0, stream>>>(f1, f2, f3, ws);
        gp_kernel<true><<<1537, NT, 0, stream>>>(verts, pc1, f1, pc2, f2, pc3, f3, ws, out);
    } else {
        gp_kernel<false><<<1537, NT, 0, stream>>>(verts, pc1, f1, pc2, f2, pc3, f3, ws, out);
    }
}